// Round 2
// baseline (344.526 us; speedup 1.0000x reference)
//
#include <hip/hip_runtime.h>
#include <hip/hip_bf16.h>
#include <math.h>

#define A_NUM 3
#define M_GT 20
#define EPSF 1e-6f
#define N_TOT 64512   // 49152 + 12288 + 3072 anchors per image
#define B_IMG 32
#define NPAIR 96      // 32 images * 3 scales

// ---------------------------------------------------------------------------
// Kernel 1: fused matching + loss for ALL three scales in one dispatch.
// grid = (84, 32): blockIdx.x 0..63 -> scale0 (H=128), 64..79 -> scale1 (H=64),
// 80..83 -> scale2 (H=32). Segment sizes (16384/4096/1024 pixels) are all
// multiples of 256, so every block is fully occupied with no bounds checks.
// thread = pixel, loops over A=3 anchors.
// Writes neg_loss[b][seg_off + pix*3 + a] = neg ? obj_loss : -1.0f
// Accumulates (atomics): sums[0]+=obj_loss(pos), sums[1]+=ce(pos),
// sums[2]+=smoothL1(pos); pos_cnt[b*3+scale] += npos.
// Anchors computed analytically — exact fp32 match to make_anchors (all values
// are multiples of 0.5 with magnitude < 512, exactly representable).
// ---------------------------------------------------------------------------
__global__ __launch_bounds__(256) void match_kernel(
    const float* __restrict__ pred1,     // (B, 24, 128, 128)
    const float* __restrict__ pred2,     // (B, 24, 64, 64)
    const float* __restrict__ pred3,     // (B, 24, 32, 32)
    const float* __restrict__ gt_boxes,  // (B, 20, 4)
    const int*   __restrict__ gt_labels, // (B, 20)
    float* __restrict__ neg_loss,        // (B, N_TOT)
    int*   __restrict__ pos_cnt,         // (96,)
    float* __restrict__ sums)            // [obj_pos, cls, loc]
{
    const int b  = blockIdx.y;
    const int bx = blockIdx.x;

    int scale, H, seg_off;
    const float* pred;
    int pixblk;
    if (bx < 64)      { scale = 0; H = 128; seg_off = 0;     pixblk = bx;      pred = pred1; }
    else if (bx < 80) { scale = 1; H = 64;  seg_off = 49152; pixblk = bx - 64; pred = pred2; }
    else              { scale = 2; H = 32;  seg_off = 61440; pixblk = bx - 80; pred = pred3; }

    const int HW  = H * H;
    const int pix = pixblk * 256 + threadIdx.x;   // always < HW

    __shared__ float s_box[M_GT][4];
    __shared__ float s_ag[M_GT];
    __shared__ int   s_lab[M_GT];
    if (threadIdx.x < M_GT) {
        int j = threadIdx.x;
        float4 g = reinterpret_cast<const float4*>(gt_boxes)[b * M_GT + j];
        s_box[j][0] = g.x; s_box[j][1] = g.y; s_box[j][2] = g.z; s_box[j][3] = g.w;
        s_ag[j] = (g.z - g.x) * (g.w - g.y);
        s_lab[j] = gt_labels[b * M_GT + j];
    }
    __syncthreads();

    const int x = pix % H;
    const int y = pix / H;
    const float stride = 256.0f / (float)H;
    const float cx = ((float)x + 0.5f) * stride;
    const float cy = ((float)y + 0.5f) * stride;

    const size_t pbase = (size_t)b * 24 * HW + pix;

    float l_obj = 0.f, l_cls = 0.f, l_loc = 0.f;
    int l_pos = 0;

    #pragma unroll
    for (int a = 0; a < A_NUM; ++a) {
        const float half = 0.5f * ((float)(a + 2) * stride);  // sizes {2,3,4}*stride, halved
        const float ax1 = cx - half, ay1 = cy - half;
        const float ax2 = cx + half, ay2 = cy + half;
        const float aa = (ax2 - ax1) * (ay2 - ay1);

        float best = -1.0f; int bj = 0;
        #pragma unroll
        for (int j = 0; j < M_GT; ++j) {
            float lx = fmaxf(ax1, s_box[j][0]);
            float ly = fmaxf(ay1, s_box[j][1]);
            float rx = fminf(ax2, s_box[j][2]);
            float ry = fminf(ay2, s_box[j][3]);
            float w  = fmaxf(rx - lx, 0.f);
            float h  = fmaxf(ry - ly, 0.f);
            float inter = w * h;
            float iou = inter / (aa + s_ag[j] - inter + EPSF);
            if (iou > best) { best = iou; bj = j; }   // strict > == first-index argmax
        }
        const bool pos = (best >= 0.5f);
        const bool neg = (best < 0.3f);

        const float po = pred[pbase + (size_t)(a * 8 + 4) * HW];
        const float t  = pos ? 1.0f : 0.0f;
        const float ol = fmaxf(po, 0.f) - po * t + log1pf(expf(-fabsf(po)));

        neg_loss[(size_t)b * N_TOT + seg_off + pix * 3 + a] = neg ? ol : -1.0f;

        if (pos) {
            l_pos += 1;
            l_obj += ol;
            // classification CE (log_softmax over 3 classes)
            float c0 = pred[pbase + (size_t)(a * 8 + 5) * HW];
            float c1 = pred[pbase + (size_t)(a * 8 + 6) * HW];
            float c2 = pred[pbase + (size_t)(a * 8 + 7) * HW];
            float m  = fmaxf(c0, fmaxf(c1, c2));
            float lse = m + logf(expf(c0 - m) + expf(c1 - m) + expf(c2 - m));
            int tgt = s_lab[bj];
            float lt = (tgt == 0) ? c0 : ((tgt == 1) ? c1 : c2);
            l_cls += lse - lt;
            // localization smooth-L1 vs encoded target
            float gx1 = s_box[bj][0], gy1 = s_box[bj][1];
            float gx2 = s_box[bj][2], gy2 = s_box[bj][3];
            float gw = fmaxf(gx2 - gx1, EPSF), gh = fmaxf(gy2 - gy1, EPSF);
            float gcx = gx1 + 0.5f * gw,  gcy = gy1 + 0.5f * gh;
            float aw = fmaxf(ax2 - ax1, EPSF), ah = fmaxf(ay2 - ay1, EPSF);
            float acx = ax1 + 0.5f * aw, acy = ay1 + 0.5f * ah;
            float tx = (gcx - acx) / (aw + EPSF);
            float ty = (gcy - acy) / (ah + EPSF);
            float tw = logf((gw + EPSF) / (aw + EPSF));
            float th = logf((gh + EPSF) / (ah + EPSF));
            float p0 = pred[pbase + (size_t)(a * 8 + 0) * HW];
            float p1 = pred[pbase + (size_t)(a * 8 + 1) * HW];
            float p2 = pred[pbase + (size_t)(a * 8 + 2) * HW];
            float p3 = pred[pbase + (size_t)(a * 8 + 3) * HW];
            float d0 = p0 - tx, d1 = p1 - ty, d2 = p2 - tw, d3 = p3 - th;
            float ad;
            ad = fabsf(d0); l_loc += (ad < 1.f) ? 0.5f * d0 * d0 : ad - 0.5f;
            ad = fabsf(d1); l_loc += (ad < 1.f) ? 0.5f * d1 * d1 : ad - 0.5f;
            ad = fabsf(d2); l_loc += (ad < 1.f) ? 0.5f * d2 * d2 : ad - 0.5f;
            ad = fabsf(d3); l_loc += (ad < 1.f) ? 0.5f * d3 * d3 : ad - 0.5f;
        }
    }

    if (l_pos) {
        atomicAdd(&pos_cnt[b * 3 + scale], l_pos);
        atomicAdd(&sums[0], l_obj);
        atomicAdd(&sums[1], l_cls);
        atomicAdd(&sums[2], l_loc);
    }
}

// ---------------------------------------------------------------------------
// Kernel 2: exact top-k sum of negative losses per (image, scale) pair via
// radix-select on float bit patterns (values > 0; -1 sentinel = not-neg).
// Ties at threshold tau contribute kr*tau — identity of tied indices is
// irrelevant to the final sums, so this matches argsort-based mining exactly.
// ---------------------------------------------------------------------------
__global__ __launch_bounds__(256) void mine_kernel(
    const float* __restrict__ neg_loss,
    const int*   __restrict__ pos_cnt,
    float* __restrict__ sel_sum,
    int*   __restrict__ sel_cnt)
{
    const int pair = blockIdx.x;         // b*3 + s
    const int s = pair % 3;
    const int b = pair / 3;
    const int seg_off_tab[3] = {0, 49152, 61440};
    const int seg_len_tab[3] = {49152, 12288, 3072};
    const float* seg = neg_loss + (size_t)b * N_TOT + seg_off_tab[s];
    const int len = seg_len_tab[s];
    const int tid = threadIdx.x;
    const int k = 3 * max(pos_cnt[pair], 1);

    __shared__ int hist[256];
    __shared__ unsigned s_prefix;
    __shared__ int s_kr, s_cg, s_numneg, s_takeall;

    if (tid == 0) { s_prefix = 0u; s_kr = k; s_cg = 0; s_takeall = 0; s_numneg = 0; }

    for (int level = 3; level >= 0; --level) {
        hist[tid] = 0;
        __syncthreads();                  // hist zeroed; init/prefix visible
        const int shift = level * 8;
        const unsigned pref = s_prefix;
        for (int i = tid; i < len; i += 256) {
            float v = seg[i];
            if (v < 0.f) continue;
            unsigned u = __float_as_uint(v);
            if (level < 3 && ((u ^ pref) >> (shift + 8)) != 0) continue;
            atomicAdd(&hist[(u >> shift) & 255], 1);
        }
        __syncthreads();
        if (tid == 0) {
            if (level == 3) {
                int tot = 0;
                for (int i = 0; i < 256; ++i) tot += hist[i];
                s_numneg = tot;
                if (k >= tot) s_takeall = 1;
            }
            if (!s_takeall) {
                int kr = s_kr, cg = s_cg;
                unsigned pr = s_prefix;
                for (int bin = 255; bin >= 0; --bin) {
                    int c = hist[bin];
                    if (kr <= c) { pr |= ((unsigned)bin) << shift; break; }
                    kr -= c; cg += c;
                }
                s_kr = kr; s_cg = cg; s_prefix = pr;
            }
        }
        __syncthreads();                  // tid0 done reading hist + flags visible
        if (s_takeall) break;
    }

    const bool takeall = (s_takeall != 0);
    const float tau = __uint_as_float(s_prefix);
    float local = 0.f;
    for (int i = tid; i < len; i += 256) {
        float v = seg[i];
        if (v < 0.f) continue;
        if (takeall || v > tau) local += v;
    }
    for (int off = 32; off > 0; off >>= 1) local += __shfl_down(local, off);
    __shared__ float part[4];
    if ((tid & 63) == 0) part[tid >> 6] = local;
    __syncthreads();
    if (tid == 0) {
        float tot = part[0] + part[1] + part[2] + part[3];
        int cnt;
        if (takeall) {
            cnt = s_numneg;
        } else {
            tot += (float)s_kr * tau;    // kr ties at tau, each contributes tau
            cnt = k;
        }
        sel_sum[pair] = tot;
        sel_cnt[pair] = cnt;
    }
}

// ---------------------------------------------------------------------------
// Kernel 3: combine. Single thread — 96 iterations, trivial.
// ---------------------------------------------------------------------------
__global__ void finalize_kernel(
    const float* __restrict__ sums,
    const int*   __restrict__ pos_cnt,
    const float* __restrict__ sel_sum,
    const int*   __restrict__ sel_cnt,
    float* __restrict__ out)
{
    float obj = sums[0], cls = sums[1], loc = sums[2];
    int den = 0, np = 0;
    for (int p = 0; p < NPAIR; ++p) {
        obj += sel_sum[p];
        den += pos_cnt[p] + sel_cnt[p];
        np  += pos_cnt[p];
    }
    float pos_norm = (float)max(np, 1);
    float obj_norm = (float)max(den, 1);
    float lo = obj / obj_norm;
    float lc = cls / pos_norm;
    float ll = loc / pos_norm;
    out[0] = lo;
    out[1] = lc;
    out[2] = ll;
    out[3] = lo + lc + 2.0f * ll;
}

// ---------------------------------------------------------------------------
extern "C" void kernel_launch(void* const* d_in, const int* in_sizes, int n_in,
                              void* d_out, int out_size, void* d_ws, size_t ws_size,
                              hipStream_t stream) {
    // setup_inputs() dict order: pred1, anchors1, pred2, anchors2, pred3,
    // anchors3, gt_boxes, gt_labels
    const float* pred1     = (const float*)d_in[0];   // (32,24,128,128)
    const float* pred2     = (const float*)d_in[2];   // (32,24,64,64)
    const float* pred3     = (const float*)d_in[4];   // (32,24,32,32)
    const float* gt_boxes  = (const float*)d_in[6];   // (32,20,4)
    const int*   gt_labels = (const int*)d_in[7];     // (32,20)
    // anchors (d_in[1],[3],[5]) are reproduced analytically (exact fp32).

    char* ws = (char*)d_ws;
    float* sums     = (float*)ws;                 // 3 floats  @ 0
    int*   pos_cnt  = (int*)(ws + 16);            // 96 ints   @ 16
    float* sel_sum  = (float*)(ws + 16 + 384);    // 96 floats @ 400
    int*   sel_cnt  = (int*)(ws + 16 + 768);      // 96 ints   @ 784 .. 1168
    float* neg_loss = (float*)(ws + 1280);        // 32*64512 floats = 8.25 MB

    hipMemsetAsync(d_ws, 0, 1280, stream);        // zero accumulators only

    match_kernel<<<dim3(84, B_IMG), 256, 0, stream>>>(
        pred1, pred2, pred3, gt_boxes, gt_labels, neg_loss, pos_cnt, sums);

    mine_kernel<<<NPAIR, 256, 0, stream>>>(neg_loss, pos_cnt, sel_sum, sel_cnt);

    finalize_kernel<<<1, 1, 0, stream>>>(sums, pos_cnt, sel_sum, sel_cnt, (float*)d_out);
}

// Round 3
// 296.583 us; speedup vs baseline: 1.1617x; 1.1617x over previous
//
#include <hip/hip_runtime.h>
#include <hip/hip_bf16.h>
#include <math.h>

#define A_NUM 3
#define M_GT 20
#define EPSF 1e-6f
#define N_TOT 64512   // 49152 + 12288 + 3072 anchors per image
#define B_IMG 32
#define NPAIR 96      // 32 images * 3 scales
#define BINS 8192     // histogram on float-bits >> 18 (positive floats: order-preserving)
#define BIN_SHIFT 18
#define TIE_CAP 2048  // tie-bin gather capacity (threshold is in the tail -> few ties)

// ---------------------------------------------------------------------------
// Kernel 1: fused matching + loss for ALL three scales in one dispatch.
// grid = (84, 32): blockIdx.x 0..63 -> scale0 (H=128), 64..79 -> scale1 (H=64),
// 80..83 -> scale2 (H=32). All segment pixel counts divide 256.
// Writes neg_loss[b][seg_off + pix*3 + a] = neg ? obj_loss : -1.0f, and builds
// per-(b,scale) 8192-bin histograms of negative-loss bit prefixes (global
// atomics). Accumulates positive obj/cls/loc sums + per-pair pos counts.
// Anchors computed analytically — exact fp32 match to make_anchors.
// ---------------------------------------------------------------------------
__global__ __launch_bounds__(256) void match_kernel(
    const float* __restrict__ pred1,     // (B, 24, 128, 128)
    const float* __restrict__ pred2,     // (B, 24, 64, 64)
    const float* __restrict__ pred3,     // (B, 24, 32, 32)
    const float* __restrict__ gt_boxes,  // (B, 20, 4)
    const int*   __restrict__ gt_labels, // (B, 20)
    float* __restrict__ neg_loss,        // (B, N_TOT)
    int*   __restrict__ hist,            // (96, BINS)
    int*   __restrict__ pos_cnt,         // (96,)
    float* __restrict__ sums)            // [obj_pos, cls, loc]
{
    const int b  = blockIdx.y;
    const int bx = blockIdx.x;

    int scale, H, seg_off;
    const float* pred;
    int pixblk;
    if (bx < 64)      { scale = 0; H = 128; seg_off = 0;     pixblk = bx;      pred = pred1; }
    else if (bx < 80) { scale = 1; H = 64;  seg_off = 49152; pixblk = bx - 64; pred = pred2; }
    else              { scale = 2; H = 32;  seg_off = 61440; pixblk = bx - 80; pred = pred3; }

    const int pair = b * 3 + scale;
    const int HW  = H * H;
    const int pix = pixblk * 256 + threadIdx.x;   // always < HW

    __shared__ float s_box[M_GT][4];
    __shared__ float s_ag[M_GT];
    __shared__ int   s_lab[M_GT];
    if (threadIdx.x < M_GT) {
        int j = threadIdx.x;
        float4 g = reinterpret_cast<const float4*>(gt_boxes)[b * M_GT + j];
        s_box[j][0] = g.x; s_box[j][1] = g.y; s_box[j][2] = g.z; s_box[j][3] = g.w;
        s_ag[j] = (g.z - g.x) * (g.w - g.y);
        s_lab[j] = gt_labels[b * M_GT + j];
    }
    __syncthreads();

    const int x = pix % H;
    const int y = pix / H;
    const float stride = 256.0f / (float)H;
    const float cx = ((float)x + 0.5f) * stride;
    const float cy = ((float)y + 0.5f) * stride;

    const size_t pbase = (size_t)b * 24 * HW + pix;

    float l_obj = 0.f, l_cls = 0.f, l_loc = 0.f;
    int l_pos = 0;

    #pragma unroll
    for (int a = 0; a < A_NUM; ++a) {
        const float half = 0.5f * ((float)(a + 2) * stride);
        const float ax1 = cx - half, ay1 = cy - half;
        const float ax2 = cx + half, ay2 = cy + half;
        const float aa = (ax2 - ax1) * (ay2 - ay1);

        float best = -1.0f; int bj = 0;
        #pragma unroll
        for (int j = 0; j < M_GT; ++j) {
            float lx = fmaxf(ax1, s_box[j][0]);
            float ly = fmaxf(ay1, s_box[j][1]);
            float rx = fminf(ax2, s_box[j][2]);
            float ry = fminf(ay2, s_box[j][3]);
            float w  = fmaxf(rx - lx, 0.f);
            float h  = fmaxf(ry - ly, 0.f);
            float inter = w * h;
            float iou = inter / (aa + s_ag[j] - inter + EPSF);
            if (iou > best) { best = iou; bj = j; }   // strict > == first-index argmax
        }
        const bool pos = (best >= 0.5f);
        const bool neg = (best < 0.3f);

        const float po = pred[pbase + (size_t)(a * 8 + 4) * HW];
        const float t  = pos ? 1.0f : 0.0f;
        const float ol = fmaxf(po, 0.f) - po * t + log1pf(expf(-fabsf(po)));

        neg_loss[(size_t)b * N_TOT + seg_off + pix * 3 + a] = neg ? ol : -1.0f;
        if (neg) {
            unsigned u = __float_as_uint(ol);
            atomicAdd(&hist[pair * BINS + (int)(u >> BIN_SHIFT)], 1);
        }

        if (pos) {
            l_pos += 1;
            l_obj += ol;
            float c0 = pred[pbase + (size_t)(a * 8 + 5) * HW];
            float c1 = pred[pbase + (size_t)(a * 8 + 6) * HW];
            float c2 = pred[pbase + (size_t)(a * 8 + 7) * HW];
            float m  = fmaxf(c0, fmaxf(c1, c2));
            float lse = m + logf(expf(c0 - m) + expf(c1 - m) + expf(c2 - m));
            int tgt = s_lab[bj];
            float lt = (tgt == 0) ? c0 : ((tgt == 1) ? c1 : c2);
            l_cls += lse - lt;
            float gx1 = s_box[bj][0], gy1 = s_box[bj][1];
            float gx2 = s_box[bj][2], gy2 = s_box[bj][3];
            float gw = fmaxf(gx2 - gx1, EPSF), gh = fmaxf(gy2 - gy1, EPSF);
            float gcx = gx1 + 0.5f * gw,  gcy = gy1 + 0.5f * gh;
            float aw = fmaxf(ax2 - ax1, EPSF), ah = fmaxf(ay2 - ay1, EPSF);
            float acx = ax1 + 0.5f * aw, acy = ay1 + 0.5f * ah;
            float tx = (gcx - acx) / (aw + EPSF);
            float ty = (gcy - acy) / (ah + EPSF);
            float tw = logf((gw + EPSF) / (aw + EPSF));
            float th = logf((gh + EPSF) / (ah + EPSF));
            float p0 = pred[pbase + (size_t)(a * 8 + 0) * HW];
            float p1 = pred[pbase + (size_t)(a * 8 + 1) * HW];
            float p2 = pred[pbase + (size_t)(a * 8 + 2) * HW];
            float p3 = pred[pbase + (size_t)(a * 8 + 3) * HW];
            float d0 = p0 - tx, d1 = p1 - ty, d2 = p2 - tw, d3 = p3 - th;
            float ad;
            ad = fabsf(d0); l_loc += (ad < 1.f) ? 0.5f * d0 * d0 : ad - 0.5f;
            ad = fabsf(d1); l_loc += (ad < 1.f) ? 0.5f * d1 * d1 : ad - 0.5f;
            ad = fabsf(d2); l_loc += (ad < 1.f) ? 0.5f * d2 * d2 : ad - 0.5f;
            ad = fabsf(d3); l_loc += (ad < 1.f) ? 0.5f * d3 * d3 : ad - 0.5f;
        }
    }

    if (l_pos) {
        atomicAdd(&pos_cnt[pair], l_pos);
        atomicAdd(&sums[0], l_obj);
        atomicAdd(&sums[1], l_cls);
        atomicAdd(&sums[2], l_loc);
    }
}

// ---------------------------------------------------------------------------
// Kernel 2: per-pair histogram scan. 96 blocks x 256 threads; each thread owns
// 32 contiguous bins. Descending suffix-scan locates the bin containing the
// k-th largest negative loss. params[p] = {takeall, tbin, kr, nneg}.
// ---------------------------------------------------------------------------
__global__ __launch_bounds__(256) void scan_kernel(
    const int* __restrict__ hist,
    const int* __restrict__ pos_cnt,
    int* __restrict__ params,      // (96,4)
    int* __restrict__ sel_cnt)     // (96,)
{
    const int p = blockIdx.x;
    const int tid = threadIdx.x;
    const int* h = hist + p * BINS;
    const int base = tid * 32;

    int csum = 0;
    #pragma unroll
    for (int i = 0; i < 32; ++i) csum += h[base + i];

    __shared__ int chunk[256];
    __shared__ int suffix[256];
    __shared__ int s_total;
    chunk[tid] = csum;
    __syncthreads();
    if (tid == 0) {
        int acc = 0;
        for (int t = 255; t >= 0; --t) { suffix[t] = acc; acc += chunk[t]; }
        s_total = acc;
    }
    __syncthreads();

    const int k = 3 * max(pos_cnt[p], 1);
    const int nneg = s_total;
    if (tid == 0) {
        params[p * 4 + 3] = nneg;
        if (k >= nneg) { params[p * 4 + 0] = 1; sel_cnt[p] = nneg; }
        else           { params[p * 4 + 0] = 0; sel_cnt[p] = k; }
    }
    if (k < nneg) {
        int cg0 = suffix[tid];
        if (cg0 < k && k <= cg0 + chunk[tid]) {   // boundary lives in my chunk
            int cg = cg0;
            for (int bin = base + 31; bin >= base; --bin) {
                int c = h[bin];
                if (cg < k && k <= cg + c) {
                    params[p * 4 + 1] = bin;      // threshold bin
                    params[p * 4 + 2] = k - cg;   // take kr elements from it
                    break;
                }
                cg += c;
            }
        }
    }
}

// ---------------------------------------------------------------------------
// Kernel 3: parallel pass over neg_loss. Sums values in bins ABOVE the
// threshold bin (or all negatives if takeall); gathers threshold-bin ties to a
// small per-pair buffer. grid (252, 32) x 256 — full occupancy.
// ---------------------------------------------------------------------------
__global__ __launch_bounds__(256) void sumgather_kernel(
    const float* __restrict__ neg_loss,
    const int*   __restrict__ params,
    float* __restrict__ sel_sum,
    int*   __restrict__ tie_cnt,
    float* __restrict__ tie_buf)
{
    const int b  = blockIdx.y;
    const int bx = blockIdx.x;
    const int s  = (bx < 192) ? 0 : (bx < 240) ? 1 : 2;
    const int p  = b * 3 + s;

    const int takeall = params[p * 4 + 0];
    const int tbin    = params[p * 4 + 1];

    const int i = bx * 256 + threadIdx.x;            // anchor index in image
    const float v = neg_loss[(size_t)b * N_TOT + i];

    float acc = 0.f;
    if (v >= 0.f) {
        unsigned u = __float_as_uint(v);
        int bin = (int)(u >> BIN_SHIFT);
        if (takeall || bin > tbin) acc = v;
        else if (bin == tbin) {
            int idx = atomicAdd(&tie_cnt[p], 1);
            if (idx < TIE_CAP) tie_buf[p * TIE_CAP + idx] = v;
        }
    }
    for (int off = 32; off > 0; off >>= 1) acc += __shfl_down(acc, off);
    __shared__ float part[4];
    if ((threadIdx.x & 63) == 0) part[threadIdx.x >> 6] = acc;
    __syncthreads();
    if (threadIdx.x == 0) {
        float bs = part[0] + part[1] + part[2] + part[3];
        if (bs != 0.f) atomicAdd(&sel_sum[p], bs);
    }
}

// ---------------------------------------------------------------------------
// Kernel 4: exact select among the gathered ties (low 18 bits, two 9-bit radix
// levels in LDS). Adds sum(values > tau) + kr_final * tau to sel_sum[p].
// ---------------------------------------------------------------------------
__global__ __launch_bounds__(256) void select_kernel(
    const int*   __restrict__ params,
    const int*   __restrict__ tie_cnt,
    const float* __restrict__ tie_buf,
    float* __restrict__ sel_sum)
{
    const int p = blockIdx.x;
    if (params[p * 4 + 0] == 1) return;   // takeall: nothing to refine

    const int kr = params[p * 4 + 2];
    const int m  = min(tie_cnt[p], TIE_CAP);
    const float* tb = tie_buf + p * TIE_CAP;
    const int tid = threadIdx.x;

    __shared__ int lh[512];
    __shared__ int s_binA, s_krA, s_binB, s_krB;

    // level A: bits [17:9]
    for (int i = tid; i < 512; i += 256) lh[i] = 0;
    __syncthreads();
    for (int i = tid; i < m; i += 256) {
        unsigned u = __float_as_uint(tb[i]);
        atomicAdd(&lh[(u >> 9) & 511], 1);
    }
    __syncthreads();
    if (tid == 0) {
        int cg = 0;
        for (int bin = 511; bin >= 0; --bin) {
            int c = lh[bin];
            if (cg < kr && kr <= cg + c) { s_binA = bin; s_krA = kr - cg; break; }
            cg += c;
        }
    }
    __syncthreads();
    const int binA = s_binA, krA = s_krA;

    // level B: bits [8:0] among prefix matches
    for (int i = tid; i < 512; i += 256) lh[i] = 0;
    __syncthreads();
    for (int i = tid; i < m; i += 256) {
        unsigned u = __float_as_uint(tb[i]);
        if (((u >> 9) & 511) == (unsigned)binA) atomicAdd(&lh[u & 511], 1);
    }
    __syncthreads();
    if (tid == 0) {
        int cg = 0;
        for (int bin = 511; bin >= 0; --bin) {
            int c = lh[bin];
            if (cg < krA && krA <= cg + c) { s_binB = bin; s_krB = krA - cg; break; }
            cg += c;
        }
    }
    __syncthreads();

    const unsigned tau_bits = ((unsigned)params[p * 4 + 1] << BIN_SHIFT)
                            | ((unsigned)binA << 9) | (unsigned)s_binB;
    const float tau = __uint_as_float(tau_bits);

    float acc = 0.f;
    for (int i = tid; i < m; i += 256) {
        float v = tb[i];
        if (__float_as_uint(v) > tau_bits) acc += v;
    }
    for (int off = 32; off > 0; off >>= 1) acc += __shfl_down(acc, off);
    __shared__ float part[4];
    if ((tid & 63) == 0) part[tid >> 6] = acc;
    __syncthreads();
    if (tid == 0)
        sel_sum[p] += part[0] + part[1] + part[2] + part[3] + (float)s_krB * tau;
}

// ---------------------------------------------------------------------------
// Kernel 5: final reduce over 96 pairs (parallel, 2 waves).
// ---------------------------------------------------------------------------
__global__ __launch_bounds__(128) void final_kernel(
    const float* __restrict__ sums,
    const int*   __restrict__ pos_cnt,
    const float* __restrict__ sel_sum,
    const int*   __restrict__ sel_cnt,
    float* __restrict__ out)
{
    const int tid = threadIdx.x;
    float fsum = 0.f; int c1 = 0, c2 = 0;
    if (tid < NPAIR) { fsum = sel_sum[tid]; c1 = pos_cnt[tid]; c2 = sel_cnt[tid]; }
    for (int off = 32; off > 0; off >>= 1) {
        fsum += __shfl_down(fsum, off);
        c1   += __shfl_down(c1, off);
        c2   += __shfl_down(c2, off);
    }
    __shared__ float fp[2]; __shared__ int i1[2], i2[2];
    if ((tid & 63) == 0) { fp[tid >> 6] = fsum; i1[tid >> 6] = c1; i2[tid >> 6] = c2; }
    __syncthreads();
    if (tid == 0) {
        float obj = sums[0] + fp[0] + fp[1];
        int np  = i1[0] + i1[1];
        int den = np + i2[0] + i2[1];
        float pos_norm = (float)max(np, 1);
        float obj_norm = (float)max(den, 1);
        float lo = obj / obj_norm;
        float lc = sums[1] / pos_norm;
        float ll = sums[2] / pos_norm;
        out[0] = lo; out[1] = lc; out[2] = ll;
        out[3] = lo + lc + 2.0f * ll;
    }
}

// ---------------------------------------------------------------------------
extern "C" void kernel_launch(void* const* d_in, const int* in_sizes, int n_in,
                              void* d_out, int out_size, void* d_ws, size_t ws_size,
                              hipStream_t stream) {
    // setup_inputs() dict order: pred1, anchors1, pred2, anchors2, pred3,
    // anchors3, gt_boxes, gt_labels
    const float* pred1     = (const float*)d_in[0];   // (32,24,128,128)
    const float* pred2     = (const float*)d_in[2];   // (32,24,64,64)
    const float* pred3     = (const float*)d_in[4];   // (32,24,32,32)
    const float* gt_boxes  = (const float*)d_in[6];   // (32,20,4)
    const int*   gt_labels = (const int*)d_in[7];     // (32,20)

    char* ws = (char*)d_ws;
    float* sums     = (float*)(ws + 0);        // 3 floats
    int*   pos_cnt  = (int*)  (ws + 16);       // 96
    float* sel_sum  = (float*)(ws + 400);      // 96
    int*   sel_cnt  = (int*)  (ws + 784);      // 96
    int*   tie_cnt  = (int*)  (ws + 1168);     // 96
    int*   params   = (int*)  (ws + 1552);     // 96*4
    int*   hist     = (int*)  (ws + 4096);                    // 96*8192 = 3 MB
    float* tie_buf  = (float*)(ws + 4096 + 96*BINS*4);        // 96*2048 = 768 KB
    float* neg_loss = (float*)(ws + 4096 + 96*BINS*4 + 96*TIE_CAP*4);  // 8.25 MB

    // zero accumulators + histograms (first 4096 + 3 MB, contiguous)
    hipMemsetAsync(d_ws, 0, 4096 + (size_t)96 * BINS * 4, stream);

    match_kernel<<<dim3(84, B_IMG), 256, 0, stream>>>(
        pred1, pred2, pred3, gt_boxes, gt_labels, neg_loss, hist, pos_cnt, sums);

    scan_kernel<<<NPAIR, 256, 0, stream>>>(hist, pos_cnt, params, sel_cnt);

    sumgather_kernel<<<dim3(252, B_IMG), 256, 0, stream>>>(
        neg_loss, params, sel_sum, tie_cnt, tie_buf);

    select_kernel<<<NPAIR, 256, 0, stream>>>(params, tie_cnt, tie_buf, sel_sum);

    final_kernel<<<1, 128, 0, stream>>>(sums, pos_cnt, sel_sum, sel_cnt, (float*)d_out);
}

// Round 5
// 289.392 us; speedup vs baseline: 1.1905x; 1.0248x over previous
//
#include <hip/hip_runtime.h>
#include <hip/hip_bf16.h>
#include <math.h>

#define M_GT 20
#define EPSF 1e-6f
#define N_TOT 64512      // 49152 + 12288 + 3072 anchors per image
#define B_IMG 32
#define NPAIR 96         // 32 images * 3 scales
#define MBINS 4096       // 12-bit key-prefix bins (LDS)
#define TIE_CAP 2048
#define SENT_BITS 0xFF800000u   // -inf sentinel (anchor not negative)

// Order-preserving float->uint key (handles negative logits).
__device__ __forceinline__ unsigned keyof(unsigned bits) {
    return (bits & 0x80000000u) ? ~bits : (bits | 0x80000000u);
}
__device__ __forceinline__ float softplus_ref(float x) {
    // exact reference formula: max(x,0) - x*t + log1p(exp(-|x|)) with t=0
    return fmaxf(x, 0.f) + log1pf(expf(-fabsf(x)));
}

// ---------------------------------------------------------------------------
// match: per-scale matching + positive losses. thread = pixel, 3 anchors each.
// Writes neg_key[b][SEG_OFF + a*HW + pix] = neg ? raw_obj_logit : -inf
// (selection on raw logits is exact: softplus is strictly monotone).
// GT y-band culling: a block covers 256/H rows; GTs that cannot intersect any
// anchor in the band are dropped (their iou is exactly 0 -> cannot affect
// pos/neg flags; best=fmax(best,0) reproduces the reference best_iou).
// ---------------------------------------------------------------------------
template<int H, int SEG_OFF>
__device__ __forceinline__ void match_scale(
    const float* __restrict__ pred,      // (B, 24, H, H)
    const float* __restrict__ gt_boxes,  // (B, 20, 4)
    const int*   __restrict__ gt_labels, // (B, 20)
    float* __restrict__ neg_key,         // (B, N_TOT)
    int*   __restrict__ pos_cnt,         // (96,)
    float* __restrict__ sums,            // [obj_pos, cls, loc]
    int pixblk, int b, int pair)
{
    constexpr int HW = H * H;
    constexpr float STRIDE = 256.0f / (float)H;
    constexpr int NROWS = 256 / H;
    const int tid = threadIdx.x;
    const int pix = pixblk * 256 + tid;          // always < HW

    __shared__ float4 s_box[M_GT];
    __shared__ float  s_ag[M_GT];
    __shared__ int    s_lab[M_GT];
    __shared__ int    s_nk;

    if (tid < 64) {                               // wave 0 only: ballot compaction
        bool keep = false;
        float4 g = make_float4(0.f, 0.f, 0.f, 0.f);
        int lab = 0;
        if (tid < M_GT) {
            g   = reinterpret_cast<const float4*>(gt_boxes)[b * M_GT + tid];
            lab = gt_labels[b * M_GT + tid];
            const int y0 = (pixblk * 256) / H;
            const float lo = ((float)y0 + 0.5f) * STRIDE - 2.0f * STRIDE;
            const float hi = ((float)(y0 + NROWS - 1) + 0.5f) * STRIDE + 2.0f * STRIDE;
            keep = (g.y < hi) && (g.w > lo);      // y-overlap possible
        }
        unsigned long long m = __ballot(keep);
        if (keep) {
            int posi = __popcll(m & ((1ull << tid) - 1ull));   // order-preserving
            s_box[posi] = g;
            s_ag[posi]  = (g.z - g.x) * (g.w - g.y);
            s_lab[posi] = lab;
        }
        if (tid == 0) s_nk = __popcll(m);
    }
    __syncthreads();
    const int nk = s_nk;

    const int x = pix % H;                        // H is constexpr -> and/shift
    const int y = pix / H;
    const float cx = ((float)x + 0.5f) * STRIDE;  // exact fp32, == make_anchors
    const float cy = ((float)y + 0.5f) * STRIDE;
    const size_t pbase = (size_t)b * 24 * HW + pix;

    float l_obj = 0.f, l_cls = 0.f, l_loc = 0.f;
    int l_pos = 0;

    #pragma unroll
    for (int a = 0; a < 3; ++a) {
        const float half = 0.5f * ((float)(a + 2) * STRIDE);
        const float ax1 = cx - half, ay1 = cy - half;
        const float ax2 = cx + half, ay2 = cy + half;
        const float aa = (ax2 - ax1) * (ay2 - ay1);

        float best = -1.0f; int bj = 0;
        for (int j = 0; j < nk; ++j) {
            float4 gb = s_box[j];
            float lx = fmaxf(ax1, gb.x);
            float ly = fmaxf(ay1, gb.y);
            float rx = fminf(ax2, gb.z);
            float ry = fminf(ay2, gb.w);
            float w  = fmaxf(rx - lx, 0.f);
            float h  = fmaxf(ry - ly, 0.f);
            float inter = w * h;
            float iou = inter / (aa + s_ag[j] - inter + EPSF);
            if (iou > best) { best = iou; bj = j; }   // first-max == argmax
        }
        best = fmaxf(best, 0.0f);                 // culled GTs contribute exactly 0
        const bool pos = (best >= 0.5f);
        const bool neg = (best < 0.3f);

        const float po = pred[pbase + (size_t)(a * 8 + 4) * HW];
        neg_key[(size_t)b * N_TOT + SEG_OFF + a * HW + pix] =
            neg ? po : __uint_as_float(SENT_BITS);

        if (pos) {
            l_pos += 1;
            l_obj += fmaxf(po, 0.f) - po + log1pf(expf(-fabsf(po)));  // t=1
            float c0 = pred[pbase + (size_t)(a * 8 + 5) * HW];
            float c1 = pred[pbase + (size_t)(a * 8 + 6) * HW];
            float c2 = pred[pbase + (size_t)(a * 8 + 7) * HW];
            float m2 = fmaxf(c0, fmaxf(c1, c2));
            float lse = m2 + logf(expf(c0 - m2) + expf(c1 - m2) + expf(c2 - m2));
            int tgt = s_lab[bj];
            float lt = (tgt == 0) ? c0 : ((tgt == 1) ? c1 : c2);
            l_cls += lse - lt;
            float4 gb = s_box[bj];
            float gw = fmaxf(gb.z - gb.x, EPSF), gh = fmaxf(gb.w - gb.y, EPSF);
            float gcx = gb.x + 0.5f * gw, gcy = gb.y + 0.5f * gh;
            float aw = fmaxf(ax2 - ax1, EPSF), ah = fmaxf(ay2 - ay1, EPSF);
            float acx = ax1 + 0.5f * aw, acy = ay1 + 0.5f * ah;
            float tx = (gcx - acx) / (aw + EPSF);
            float ty = (gcy - acy) / (ah + EPSF);
            float tw = logf((gw + EPSF) / (aw + EPSF));
            float th = logf((gh + EPSF) / (ah + EPSF));
            float p0 = pred[pbase + (size_t)(a * 8 + 0) * HW];
            float p1 = pred[pbase + (size_t)(a * 8 + 1) * HW];
            float p2 = pred[pbase + (size_t)(a * 8 + 2) * HW];
            float p3 = pred[pbase + (size_t)(a * 8 + 3) * HW];
            float d0 = p0 - tx, d1 = p1 - ty, d2 = p2 - tw, d3 = p3 - th;
            float ad;
            ad = fabsf(d0); l_loc += (ad < 1.f) ? 0.5f * d0 * d0 : ad - 0.5f;
            ad = fabsf(d1); l_loc += (ad < 1.f) ? 0.5f * d1 * d1 : ad - 0.5f;
            ad = fabsf(d2); l_loc += (ad < 1.f) ? 0.5f * d2 * d2 : ad - 0.5f;
            ad = fabsf(d3); l_loc += (ad < 1.f) ? 0.5f * d3 * d3 : ad - 0.5f;
        }
    }

    if (l_pos) {
        atomicAdd(&pos_cnt[pair], l_pos);
        atomicAdd(&sums[0], l_obj);
        atomicAdd(&sums[1], l_cls);
        atomicAdd(&sums[2], l_loc);
    }
}

__global__ __launch_bounds__(256) void match_kernel(
    const float* __restrict__ pred1, const float* __restrict__ pred2,
    const float* __restrict__ pred3, const float* __restrict__ gt_boxes,
    const int* __restrict__ gt_labels, float* __restrict__ neg_key,
    int* __restrict__ pos_cnt, float* __restrict__ sums)
{
    const int b  = blockIdx.y;
    const int bx = blockIdx.x;
    if (bx < 64)
        match_scale<128, 0>(pred1, gt_boxes, gt_labels, neg_key, pos_cnt, sums, bx, b, b * 3 + 0);
    else if (bx < 80)
        match_scale<64, 49152>(pred2, gt_boxes, gt_labels, neg_key, pos_cnt, sums, bx - 64, b, b * 3 + 1);
    else
        match_scale<32, 61440>(pred3, gt_boxes, gt_labels, neg_key, pos_cnt, sums, bx - 80, b, b * 3 + 2);
}

// ---------------------------------------------------------------------------
// mine: one block per (image, scale) pair. LDS histogram of key top-12 bits ->
// suffix scan -> sum softplus above threshold bin + gather ties -> exact 2x10
// bit LDS radix on ties -> publish via device-scope atomics; last block done
// computes the final 4 outputs (all cross-block comm via device-scope atomics).
// ---------------------------------------------------------------------------
__global__ __launch_bounds__(256) void mine_kernel(
    const float* __restrict__ neg_key,
    int*   pos_cnt,     // non-const: atomic reads in final reduce
    float* sums,
    int*   done,
    float* sel_sum,
    int*   sel_cnt,
    float* __restrict__ out)
{
    const int p = blockIdx.x;
    const int s = p % 3;
    const int b = p / 3;
    const int seg_off = (s == 0) ? 0 : (s == 1) ? 49152 : 61440;
    const int len4    = ((s == 0) ? 49152 : (s == 1) ? 12288 : 3072) >> 2;
    const float4* seg4 =
        reinterpret_cast<const float4*>(neg_key + (size_t)b * N_TOT + seg_off);
    const int tid = threadIdx.x;

    __shared__ int   hist[MBINS];       // 16 KB (reused as 1024-bin radix hist)
    __shared__ int   chunk[256], sufx[256];
    __shared__ float ties[TIE_CAP];     // 8 KB
    __shared__ float part[4];
    __shared__ int s_tcnt, s_tbin, s_kr, s_nneg, s_binA, s_krA, s_binB, s_krB, s_last;

    for (int i = tid; i < MBINS; i += 256) hist[i] = 0;
    if (tid == 0) { s_tcnt = 0; s_tbin = -1; s_kr = 0; }
    __syncthreads();

    // phase 1: histogram of key prefix
    for (int i = tid; i < len4; i += 256) {
        float4 v4 = seg4[i];
        const float vs[4] = {v4.x, v4.y, v4.z, v4.w};
        #pragma unroll
        for (int c = 0; c < 4; ++c) {
            unsigned ub = __float_as_uint(vs[c]);
            if (ub != SENT_BITS) atomicAdd(&hist[keyof(ub) >> 20], 1);
        }
    }
    __syncthreads();

    // phase 2: suffix scan to locate threshold bin
    int csum = 0;
    #pragma unroll
    for (int i = 0; i < 16; ++i) csum += hist[tid * 16 + i];
    chunk[tid] = csum;
    __syncthreads();
    if (tid == 0) {
        int acc = 0;
        for (int t = 255; t >= 0; --t) { sufx[t] = acc; acc += chunk[t]; }
        s_nneg = acc;
    }
    __syncthreads();
    const int k = 3 * max(pos_cnt[p], 1);
    const int nneg = s_nneg;
    const bool takeall = (k >= nneg);
    if (!takeall) {
        int cg0 = sufx[tid];
        if (cg0 < k && k <= cg0 + chunk[tid]) {        // exactly one thread
            int cg = cg0;
            for (int bin = tid * 16 + 15; bin >= tid * 16; --bin) {
                int c = hist[bin];
                if (cg < k && k <= cg + c) { s_tbin = bin; s_kr = k - cg; break; }
                cg += c;
            }
        }
    }
    __syncthreads();
    const int tbin = s_tbin;

    // phase 3: sum softplus above threshold bin; gather tie-bin values to LDS
    float acc = 0.f;
    for (int i = tid; i < len4; i += 256) {
        float4 v4 = seg4[i];
        const float vs[4] = {v4.x, v4.y, v4.z, v4.w};
        #pragma unroll
        for (int c = 0; c < 4; ++c) {
            float v = vs[c];
            unsigned ub = __float_as_uint(v);
            if (ub == SENT_BITS) continue;
            int bin = (int)(keyof(ub) >> 20);
            if (takeall || bin > tbin) acc += softplus_ref(v);
            else if (bin == tbin) {
                int idx = atomicAdd(&s_tcnt, 1);
                if (idx < TIE_CAP) ties[idx] = v;
            }
        }
    }
    for (int off = 32; off > 0; off >>= 1) acc += __shfl_down(acc, off);
    if ((tid & 63) == 0) part[tid >> 6] = acc;
    __syncthreads();
    const float blocksum = part[0] + part[1] + part[2] + part[3];

    // phase 4: exact tie resolution
    float extra = 0.f;
    int selcnt;
    if (takeall) {
        selcnt = nneg;
    } else {
        const int m  = min(s_tcnt, TIE_CAP);
        const int kr = s_kr;
        for (int i = tid; i < 1024; i += 256) hist[i] = 0;
        __syncthreads();
        for (int i = tid; i < m; i += 256) {
            unsigned key = keyof(__float_as_uint(ties[i]));
            atomicAdd(&hist[(key >> 10) & 1023], 1);
        }
        __syncthreads();
        if (tid == 0) {
            int cg = 0;
            for (int bin = 1023; bin >= 0; --bin) {
                int c = hist[bin];
                if (cg < kr && kr <= cg + c) { s_binA = bin; s_krA = kr - cg; break; }
                cg += c;
            }
        }
        __syncthreads();
        const int binA = s_binA, krA = s_krA;
        for (int i = tid; i < 1024; i += 256) hist[i] = 0;
        __syncthreads();
        for (int i = tid; i < m; i += 256) {
            unsigned key = keyof(__float_as_uint(ties[i]));
            if (((key >> 10) & 1023) == (unsigned)binA) atomicAdd(&hist[key & 1023], 1);
        }
        __syncthreads();
        if (tid == 0) {
            int cg = 0;
            for (int bin = 1023; bin >= 0; --bin) {
                int c = hist[bin];
                if (cg < krA && krA <= cg + c) { s_binB = bin; s_krB = krA - cg; break; }
                cg += c;
            }
        }
        __syncthreads();
        const unsigned tkey = (((unsigned)tbin) << 20) | (((unsigned)binA) << 10)
                            | (unsigned)s_binB;
        float acc2 = 0.f;
        for (int i = tid; i < m; i += 256) {
            float v = ties[i];
            if (keyof(__float_as_uint(v)) > tkey) acc2 += softplus_ref(v);
        }
        for (int off = 32; off > 0; off >>= 1) acc2 += __shfl_down(acc2, off);
        __syncthreads();                         // part[] reuse
        if ((tid & 63) == 0) part[tid >> 6] = acc2;
        __syncthreads();
        const unsigned tb = (tkey & 0x80000000u) ? (tkey & 0x7FFFFFFFu) : ~tkey;
        const float tv = __uint_as_float(tb);    // exact tie logit
        extra = part[0] + part[1] + part[2] + part[3] + (float)s_krB * softplus_ref(tv);
        selcnt = k;
    }

    // publish (device-scope atomics -> coherence point), then last-block final
    if (tid == 0) {
        atomicExch(&sel_sum[p], blocksum + extra);
        atomicExch(&sel_cnt[p], selcnt);
        __threadfence();
        int old = atomicAdd(done, 1);
        s_last = (old == NPAIR - 1) ? 1 : 0;
    }
    __syncthreads();
    if (s_last) {
        __threadfence();
        float fs = 0.f; int c1 = 0, c2 = 0;
        if (tid < NPAIR) {
            fs = atomicAdd(&sel_sum[tid], 0.0f);   // coherent reads
            c1 = atomicAdd(&pos_cnt[tid], 0);
            c2 = atomicAdd(&sel_cnt[tid], 0);
        }
        for (int off = 32; off > 0; off >>= 1) {
            fs += __shfl_down(fs, off);
            c1 += __shfl_down(c1, off);
            c2 += __shfl_down(c2, off);
        }
        __shared__ float fp2[4]; __shared__ int i1[4], i2[4];
        if ((tid & 63) == 0) { fp2[tid >> 6] = fs; i1[tid >> 6] = c1; i2[tid >> 6] = c2; }
        __syncthreads();
        if (tid == 0) {
            float obj = atomicAdd(&sums[0], 0.0f) + fp2[0] + fp2[1] + fp2[2] + fp2[3];
            float clsum = atomicAdd(&sums[1], 0.0f);
            float locsum = atomicAdd(&sums[2], 0.0f);
            int np  = i1[0] + i1[1] + i1[2] + i1[3];
            int den = np + i2[0] + i2[1] + i2[2] + i2[3];
            float pn = (float)max(np, 1);
            float on = (float)max(den, 1);
            float lo = obj / on, lc = clsum / pn, ll = locsum / pn;
            out[0] = lo; out[1] = lc; out[2] = ll;
            out[3] = lo + lc + 2.0f * ll;
        }
    }
}

// ---------------------------------------------------------------------------
extern "C" void kernel_launch(void* const* d_in, const int* in_sizes, int n_in,
                              void* d_out, int out_size, void* d_ws, size_t ws_size,
                              hipStream_t stream) {
    // setup_inputs() dict order: pred1, anchors1, pred2, anchors2, pred3,
    // anchors3, gt_boxes, gt_labels
    const float* pred1     = (const float*)d_in[0];   // (32,24,128,128)
    const float* pred2     = (const float*)d_in[2];   // (32,24,64,64)
    const float* pred3     = (const float*)d_in[4];   // (32,24,32,32)
    const float* gt_boxes  = (const float*)d_in[6];   // (32,20,4)
    const int*   gt_labels = (const int*)d_in[7];     // (32,20)

    char* ws = (char*)d_ws;
    float* sums    = (float*)(ws + 0);      // 3 floats
    int*   pos_cnt = (int*)  (ws + 16);     // 96 ints
    int*   done    = (int*)  (ws + 400);    // 1 int
    float* sel_sum = (float*)(ws + 512);    // 96 floats (atomicExch-published)
    int*   sel_cnt = (int*)  (ws + 896);    // 96 ints   (atomicExch-published)
    float* neg_key = (float*)(ws + 1280);   // 32*64512 floats = 8.25 MB

    hipMemsetAsync(d_ws, 0, 512, stream);   // sums + pos_cnt + done

    match_kernel<<<dim3(84, B_IMG), 256, 0, stream>>>(
        pred1, pred2, pred3, gt_boxes, gt_labels, neg_key, pos_cnt, sums);

    mine_kernel<<<NPAIR, 256, 0, stream>>>(
        neg_key, pos_cnt, sums, done, sel_sum, sel_cnt, (float*)d_out);
}

// Round 6
// 139.760 us; speedup vs baseline: 2.4651x; 2.0706x over previous
//
#include <hip/hip_runtime.h>
#include <hip/hip_bf16.h>
#include <math.h>

#define M_GT 20
#define EPSF 1e-6f
#define N_TOT 64512      // 49152 + 12288 + 3072 anchors per image
#define B_IMG 32
#define NPAIR 96         // 32 images * 3 scales
#define MBINS 4096       // 12-bit key-prefix bins (LDS)
#define TIE_CAP 2048
#define MT 1024          // mine_kernel block size (16 waves)
#define SENT_BITS 0xFF800000u   // -inf sentinel (anchor not negative)

// Order-preserving float->uint key (handles negative logits).
__device__ __forceinline__ unsigned keyof(unsigned bits) {
    return (bits & 0x80000000u) ? ~bits : (bits | 0x80000000u);
}
__device__ __forceinline__ float softplus_ref(float x) {
    // exact reference formula: max(x,0) - x*t + log1p(exp(-|x|)) with t=0
    return fmaxf(x, 0.f) + log1pf(expf(-fabsf(x)));
}

// ---------------------------------------------------------------------------
// match: per-scale matching + positive losses. thread = pixel, 3 anchors each.
// Writes neg_key[b][SEG_OFF + a*HW + pix] = neg ? raw_obj_logit : -inf
// (selection on raw logits is exact: softplus is strictly monotone).
// GT y-band culling: culled GTs have IoU == 0 exactly; best=fmax(best,0)
// reproduces reference best_iou; argmax-first-index preserved (compaction is
// order-preserving and culled GTs can never reach IoU >= 0.5).
// ---------------------------------------------------------------------------
template<int H, int SEG_OFF>
__device__ __forceinline__ void match_scale(
    const float* __restrict__ pred,      // (B, 24, H, H)
    const float* __restrict__ gt_boxes,  // (B, 20, 4)
    const int*   __restrict__ gt_labels, // (B, 20)
    float* __restrict__ neg_key,         // (B, N_TOT)
    int*   __restrict__ pos_cnt,         // (96,)
    float* __restrict__ sums,            // [obj_pos, cls, loc]
    int pixblk, int b, int pair)
{
    constexpr int HW = H * H;
    constexpr float STRIDE = 256.0f / (float)H;
    constexpr int NROWS = 256 / H;
    const int tid = threadIdx.x;
    const int pix = pixblk * 256 + tid;          // always < HW

    __shared__ float4 s_box[M_GT];
    __shared__ float  s_ag[M_GT];
    __shared__ int    s_lab[M_GT];
    __shared__ int    s_nk;

    if (tid < 64) {                               // wave 0 only: ballot compaction
        bool keep = false;
        float4 g = make_float4(0.f, 0.f, 0.f, 0.f);
        int lab = 0;
        if (tid < M_GT) {
            g   = reinterpret_cast<const float4*>(gt_boxes)[b * M_GT + tid];
            lab = gt_labels[b * M_GT + tid];
            const int y0 = (pixblk * 256) / H;
            const float lo = ((float)y0 + 0.5f) * STRIDE - 2.0f * STRIDE;
            const float hi = ((float)(y0 + NROWS - 1) + 0.5f) * STRIDE + 2.0f * STRIDE;
            keep = (g.y < hi) && (g.w > lo);      // y-overlap possible
        }
        unsigned long long m = __ballot(keep);
        if (keep) {
            int posi = __popcll(m & ((1ull << tid) - 1ull));   // order-preserving
            s_box[posi] = g;
            s_ag[posi]  = (g.z - g.x) * (g.w - g.y);
            s_lab[posi] = lab;
        }
        if (tid == 0) s_nk = __popcll(m);
    }
    __syncthreads();
    const int nk = s_nk;

    const int x = pix % H;                        // H is constexpr -> and/shift
    const int y = pix / H;
    const float cx = ((float)x + 0.5f) * STRIDE;  // exact fp32, == make_anchors
    const float cy = ((float)y + 0.5f) * STRIDE;
    const size_t pbase = (size_t)b * 24 * HW + pix;

    float l_obj = 0.f, l_cls = 0.f, l_loc = 0.f;
    int l_pos = 0;

    #pragma unroll
    for (int a = 0; a < 3; ++a) {
        const float half = 0.5f * ((float)(a + 2) * STRIDE);
        const float ax1 = cx - half, ay1 = cy - half;
        const float ax2 = cx + half, ay2 = cy + half;
        const float aa = (ax2 - ax1) * (ay2 - ay1);

        float best = -1.0f; int bj = 0;
        for (int j = 0; j < nk; ++j) {
            float4 gb = s_box[j];
            float lx = fmaxf(ax1, gb.x);
            float ly = fmaxf(ay1, gb.y);
            float rx = fminf(ax2, gb.z);
            float ry = fminf(ay2, gb.w);
            float w  = fmaxf(rx - lx, 0.f);
            float h  = fmaxf(ry - ly, 0.f);
            float inter = w * h;
            float iou = inter / (aa + s_ag[j] - inter + EPSF);
            if (iou > best) { best = iou; bj = j; }   // first-max == argmax
        }
        best = fmaxf(best, 0.0f);                 // culled GTs contribute exactly 0
        const bool pos = (best >= 0.5f);
        const bool neg = (best < 0.3f);

        const float po = pred[pbase + (size_t)(a * 8 + 4) * HW];
        neg_key[(size_t)b * N_TOT + SEG_OFF + a * HW + pix] =
            neg ? po : __uint_as_float(SENT_BITS);

        if (pos) {
            l_pos += 1;
            l_obj += fmaxf(po, 0.f) - po + log1pf(expf(-fabsf(po)));  // t=1
            float c0 = pred[pbase + (size_t)(a * 8 + 5) * HW];
            float c1 = pred[pbase + (size_t)(a * 8 + 6) * HW];
            float c2 = pred[pbase + (size_t)(a * 8 + 7) * HW];
            float m2 = fmaxf(c0, fmaxf(c1, c2));
            float lse = m2 + logf(expf(c0 - m2) + expf(c1 - m2) + expf(c2 - m2));
            int tgt = s_lab[bj];
            float lt = (tgt == 0) ? c0 : ((tgt == 1) ? c1 : c2);
            l_cls += lse - lt;
            float4 gb = s_box[bj];
            float gw = fmaxf(gb.z - gb.x, EPSF), gh = fmaxf(gb.w - gb.y, EPSF);
            float gcx = gb.x + 0.5f * gw, gcy = gb.y + 0.5f * gh;
            float aw = fmaxf(ax2 - ax1, EPSF), ah = fmaxf(ay2 - ay1, EPSF);
            float acx = ax1 + 0.5f * aw, acy = ay1 + 0.5f * ah;
            float tx = (gcx - acx) / (aw + EPSF);
            float ty = (gcy - acy) / (ah + EPSF);
            float tw = logf((gw + EPSF) / (aw + EPSF));
            float th = logf((gh + EPSF) / (ah + EPSF));
            float p0 = pred[pbase + (size_t)(a * 8 + 0) * HW];
            float p1 = pred[pbase + (size_t)(a * 8 + 1) * HW];
            float p2 = pred[pbase + (size_t)(a * 8 + 2) * HW];
            float p3 = pred[pbase + (size_t)(a * 8 + 3) * HW];
            float d0 = p0 - tx, d1 = p1 - ty, d2 = p2 - tw, d3 = p3 - th;
            float ad;
            ad = fabsf(d0); l_loc += (ad < 1.f) ? 0.5f * d0 * d0 : ad - 0.5f;
            ad = fabsf(d1); l_loc += (ad < 1.f) ? 0.5f * d1 * d1 : ad - 0.5f;
            ad = fabsf(d2); l_loc += (ad < 1.f) ? 0.5f * d2 * d2 : ad - 0.5f;
            ad = fabsf(d3); l_loc += (ad < 1.f) ? 0.5f * d3 * d3 : ad - 0.5f;
        }
    }

    if (l_pos) {
        atomicAdd(&pos_cnt[pair], l_pos);
        atomicAdd(&sums[0], l_obj);
        atomicAdd(&sums[1], l_cls);
        atomicAdd(&sums[2], l_loc);
    }
}

__global__ __launch_bounds__(256) void match_kernel(
    const float* __restrict__ pred1, const float* __restrict__ pred2,
    const float* __restrict__ pred3, const float* __restrict__ gt_boxes,
    const int* __restrict__ gt_labels, float* __restrict__ neg_key,
    int* __restrict__ pos_cnt, float* __restrict__ sums)
{
    const int b  = blockIdx.y;
    const int bx = blockIdx.x;
    if (bx < 64)
        match_scale<128, 0>(pred1, gt_boxes, gt_labels, neg_key, pos_cnt, sums, bx, b, b * 3 + 0);
    else if (bx < 80)
        match_scale<64, 49152>(pred2, gt_boxes, gt_labels, neg_key, pos_cnt, sums, bx - 64, b, b * 3 + 1);
    else
        match_scale<32, 61440>(pred3, gt_boxes, gt_labels, neg_key, pos_cnt, sums, bx - 80, b, b * 3 + 2);
}

// ---------------------------------------------------------------------------
// Inclusive suffix-scan of x over 1024 threads (16 waves): intra-wave shfl
// suffix (6 steps, no barriers) + wave-total combine. Returns sum x[tid..1023];
// *tot_out = sum over all. Two barriers total (entry barrier protects wtot
// reuse across consecutive calls).
// ---------------------------------------------------------------------------
__device__ __forceinline__ int suffix_scan_1024(int x, int* wtot, int tid, int* tot_out) {
    const int lane = tid & 63, w = tid >> 6;
    int v = x;
    #pragma unroll
    for (int off = 1; off < 64; off <<= 1) {
        int u = __shfl_down(v, off);
        if (lane + off < 64) v += u;
    }
    __syncthreads();                 // protect wtot from previous use
    if (lane == 0) wtot[w] = v;      // wave suffix-total (lane0 covers whole wave)
    __syncthreads();
    int add = 0, tot = 0;
    #pragma unroll
    for (int j = 0; j < 16; ++j) {
        int t = wtot[j];
        tot += t;
        if (j > w) add += t;
    }
    *tot_out = tot;
    return v + add;
}

// ---------------------------------------------------------------------------
// mine v3: one 1024-thread block per (image, scale). Two MLP-unrolled global
// passes; parallel scans; exact 2x10-bit tie radix; last-block final output.
// ---------------------------------------------------------------------------
__global__ __launch_bounds__(MT) void mine_kernel(
    const float* __restrict__ neg_key,
    int*   pos_cnt,     // non-const: atomic reads in final reduce
    float* sums,
    int*   done,
    float* sel_sum,
    int*   sel_cnt,
    float* __restrict__ out)
{
    const int p = blockIdx.x;         // b*3 + s
    const int s = p % 3;
    const int b = p / 3;
    const int seg_off = (s == 0) ? 0 : (s == 1) ? 49152 : 61440;
    const int len4    = ((s == 0) ? 49152 : (s == 1) ? 12288 : 3072) >> 2;
    const float4* seg4 =
        reinterpret_cast<const float4*>(neg_key + (size_t)b * N_TOT + seg_off);
    const int tid = threadIdx.x;

    __shared__ int   hist[MBINS];     // 16 KB (reused for 1024-bin tie radix)
    __shared__ int   wtot[16];
    __shared__ float ties[TIE_CAP];   // 8 KB
    __shared__ float wpart[16];
    __shared__ int s_tcnt, s_tbin, s_kr, s_binA, s_krA, s_binB, s_krB, s_last;

    for (int i = tid; i < MBINS; i += MT) hist[i] = 0;
    if (tid == 0) s_tcnt = 0;
    __syncthreads();

    // ---- phase 1: histogram of key top-12 bits (4-deep unrolled loads) ----
    auto proc1 = [&](float x) {
        unsigned ub = __float_as_uint(x);
        if (ub != SENT_BITS) atomicAdd(&hist[keyof(ub) >> 20], 1);
    };
    {
        int i = tid;
        for (; i + 3 * MT < len4; i += 4 * MT) {
            float4 a0 = seg4[i], a1 = seg4[i + MT], a2 = seg4[i + 2 * MT], a3 = seg4[i + 3 * MT];
            proc1(a0.x); proc1(a0.y); proc1(a0.z); proc1(a0.w);
            proc1(a1.x); proc1(a1.y); proc1(a1.z); proc1(a1.w);
            proc1(a2.x); proc1(a2.y); proc1(a2.z); proc1(a2.w);
            proc1(a3.x); proc1(a3.y); proc1(a3.z); proc1(a3.w);
        }
        for (; i < len4; i += MT) {
            float4 a0 = seg4[i];
            proc1(a0.x); proc1(a0.y); proc1(a0.z); proc1(a0.w);
        }
    }
    __syncthreads();

    // ---- phase 2: parallel suffix scan locates threshold bin ----
    const int b0 = tid * 4;
    const int my = hist[b0] + hist[b0 + 1] + hist[b0 + 2] + hist[b0 + 3];
    int nneg;
    const int incl = suffix_scan_1024(my, wtot, tid, &nneg);
    const int k = 3 * max(pos_cnt[p], 1);
    const bool ta = (k >= nneg);
    if (!ta && (incl - my) < k && k <= incl) {    // boundary in my 4-bin chunk
        int cg = incl - my;                        // count strictly above chunk
        for (int bin = b0 + 3; bin >= b0; --bin) {
            int c = hist[bin];
            if (cg < k && k <= cg + c) { s_tbin = bin; s_kr = k - cg; break; }
            cg += c;
        }
    }
    __syncthreads();
    const int tbin = ta ? 0 : s_tbin;

    // ---- phase 3: sum softplus above tbin; gather tie-bin values ----
    float acc = 0.f;
    auto proc3 = [&](float x) {
        unsigned ub = __float_as_uint(x);
        if (ub == SENT_BITS) return;
        int bin = (int)(keyof(ub) >> 20);
        if (ta || bin > tbin) acc += softplus_ref(x);
        else if (bin == tbin) {
            int idx = atomicAdd(&s_tcnt, 1);
            if (idx < TIE_CAP) ties[idx] = x;
        }
    };
    {
        int i = tid;
        for (; i + 3 * MT < len4; i += 4 * MT) {
            float4 a0 = seg4[i], a1 = seg4[i + MT], a2 = seg4[i + 2 * MT], a3 = seg4[i + 3 * MT];
            proc3(a0.x); proc3(a0.y); proc3(a0.z); proc3(a0.w);
            proc3(a1.x); proc3(a1.y); proc3(a1.z); proc3(a1.w);
            proc3(a2.x); proc3(a2.y); proc3(a2.z); proc3(a2.w);
            proc3(a3.x); proc3(a3.y); proc3(a3.z); proc3(a3.w);
        }
        for (; i < len4; i += MT) {
            float4 a0 = seg4[i];
            proc3(a0.x); proc3(a0.y); proc3(a0.z); proc3(a0.w);
        }
    }
    #pragma unroll
    for (int off = 32; off > 0; off >>= 1) acc += __shfl_down(acc, off);
    __syncthreads();                  // all gathers done; s_tcnt final
    if ((tid & 63) == 0) wpart[tid >> 6] = acc;
    __syncthreads();
    float blocksum = 0.f;
    if (tid == 0) {
        #pragma unroll
        for (int j = 0; j < 16; ++j) blocksum += wpart[j];
    }

    // ---- phase 4: exact tie resolution (1 bin/thread, two 10-bit levels) ----
    float extra = 0.f;
    const int selcnt = ta ? nneg : k;
    if (!ta) {
        const int m  = min(s_tcnt, TIE_CAP);
        const int kr = s_kr;
        // level A: key bits [19:10]
        hist[tid] = 0;
        __syncthreads();
        for (int i = tid; i < m; i += MT)
            atomicAdd(&hist[(keyof(__float_as_uint(ties[i])) >> 10) & 1023], 1);
        __syncthreads();
        {
            int myA = hist[tid], totA;
            int inclA = suffix_scan_1024(myA, wtot, tid, &totA);
            if ((inclA - myA) < kr && kr <= inclA) { s_binA = tid; s_krA = kr - (inclA - myA); }
        }
        __syncthreads();
        const int binA = s_binA, krA = s_krA;
        // level B: key bits [9:0] among prefix matches
        hist[tid] = 0;
        __syncthreads();
        for (int i = tid; i < m; i += MT) {
            unsigned key = keyof(__float_as_uint(ties[i]));
            if (((key >> 10) & 1023) == (unsigned)binA) atomicAdd(&hist[key & 1023], 1);
        }
        __syncthreads();
        {
            int myB = hist[tid], totB;
            int inclB = suffix_scan_1024(myB, wtot, tid, &totB);
            if ((inclB - myB) < krA && krA <= inclB) { s_binB = tid; s_krB = krA - (inclB - myB); }
        }
        __syncthreads();
        const unsigned tkey = (((unsigned)tbin) << 20) | (((unsigned)binA) << 10)
                            | (unsigned)s_binB;
        float acc2 = 0.f;
        for (int i = tid; i < m; i += MT) {
            float x = ties[i];
            if (keyof(__float_as_uint(x)) > tkey) acc2 += softplus_ref(x);
        }
        #pragma unroll
        for (int off = 32; off > 0; off >>= 1) acc2 += __shfl_down(acc2, off);
        __syncthreads();              // protect wpart reuse (tid0 read blocksum)
        if ((tid & 63) == 0) wpart[tid >> 6] = acc2;
        __syncthreads();
        if (tid == 0) {
            float e2 = 0.f;
            #pragma unroll
            for (int j = 0; j < 16; ++j) e2 += wpart[j];
            const unsigned tb2 = (tkey & 0x80000000u) ? (tkey & 0x7FFFFFFFu) : ~tkey;
            extra = e2 + (float)s_krB * softplus_ref(__uint_as_float(tb2));
        }
    }

    // ---- publish + last-block final output ----
    if (tid == 0) {
        atomicExch(&sel_sum[p], blocksum + extra);
        atomicExch(&sel_cnt[p], selcnt);
        __threadfence();
        int old = atomicAdd(done, 1);
        s_last = (old == NPAIR - 1) ? 1 : 0;
    }
    __syncthreads();
    if (s_last) {
        __threadfence();
        float fs = 0.f; int c1 = 0, c2 = 0;
        if (tid < NPAIR) {
            fs = atomicAdd(&sel_sum[tid], 0.0f);   // coherent reads
            c1 = atomicAdd(&pos_cnt[tid], 0);
            c2 = atomicAdd(&sel_cnt[tid], 0);
        }
        #pragma unroll
        for (int off = 32; off > 0; off >>= 1) {
            fs += __shfl_down(fs, off);
            c1 += __shfl_down(c1, off);
            c2 += __shfl_down(c2, off);
        }
        __shared__ float f2[16]; __shared__ int a2[16], b2[16];
        if ((tid & 63) == 0) { f2[tid >> 6] = fs; a2[tid >> 6] = c1; b2[tid >> 6] = c2; }
        __syncthreads();
        if (tid == 0) {
            float obj    = atomicAdd(&sums[0], 0.0f) + f2[0] + f2[1];
            float clsum  = atomicAdd(&sums[1], 0.0f);
            float locsum = atomicAdd(&sums[2], 0.0f);
            int np  = a2[0] + a2[1];
            int den = np + b2[0] + b2[1];
            float pn = (float)max(np, 1);
            float on = (float)max(den, 1);
            float lo = obj / on, lc = clsum / pn, ll = locsum / pn;
            out[0] = lo; out[1] = lc; out[2] = ll;
            out[3] = lo + lc + 2.0f * ll;
        }
    }
}

// ---------------------------------------------------------------------------
extern "C" void kernel_launch(void* const* d_in, const int* in_sizes, int n_in,
                              void* d_out, int out_size, void* d_ws, size_t ws_size,
                              hipStream_t stream) {
    // setup_inputs() dict order: pred1, anchors1, pred2, anchors2, pred3,
    // anchors3, gt_boxes, gt_labels
    const float* pred1     = (const float*)d_in[0];   // (32,24,128,128)
    const float* pred2     = (const float*)d_in[2];   // (32,24,64,64)
    const float* pred3     = (const float*)d_in[4];   // (32,24,32,32)
    const float* gt_boxes  = (const float*)d_in[6];   // (32,20,4)
    const int*   gt_labels = (const int*)d_in[7];     // (32,20)

    char* ws = (char*)d_ws;
    float* sums    = (float*)(ws + 0);      // 3 floats
    int*   pos_cnt = (int*)  (ws + 16);     // 96 ints
    int*   done    = (int*)  (ws + 400);    // 1 int
    float* sel_sum = (float*)(ws + 512);    // 96 floats (atomicExch-published)
    int*   sel_cnt = (int*)  (ws + 896);    // 96 ints   (atomicExch-published)
    float* neg_key = (float*)(ws + 1280);   // 32*64512 floats = 8.25 MB

    hipMemsetAsync(d_ws, 0, 512, stream);   // sums + pos_cnt + done

    match_kernel<<<dim3(84, B_IMG), 256, 0, stream>>>(
        pred1, pred2, pred3, gt_boxes, gt_labels, neg_key, pos_cnt, sums);

    mine_kernel<<<NPAIR, MT, 0, stream>>>(
        neg_key, pos_cnt, sums, done, sel_sum, sel_cnt, (float*)d_out);
}

// Round 8
// 137.535 us; speedup vs baseline: 2.5050x; 1.0162x over previous
//
#include <hip/hip_runtime.h>
#include <hip/hip_bf16.h>
#include <math.h>

#define M_GT 20
#define EPSF 1e-6f
#define N_TOT 64512      // 49152 + 12288 + 3072 anchors per image
#define B_IMG 32
#define NPAIR 96         // 32 images * 3 scales
#define MBINS 4096       // 12-bit key-prefix bins (LDS)
#define TIE_CAP 2048
#define MT 1024          // mine_kernel block size (16 waves)
#define SENT_BITS 0xFF800000u   // -inf sentinel (anchor not negative)

// Order-preserving float->uint key (handles negative logits).
__device__ __forceinline__ unsigned keyof(unsigned bits) {
    return (bits & 0x80000000u) ? ~bits : (bits | 0x80000000u);
}
__device__ __forceinline__ float softplus_ref(float x) {
    // exact reference formula: max(x,0) - x*t + log1p(exp(-|x|)) with t=0
    return fmaxf(x, 0.f) + log1pf(expf(-fabsf(x)));
}

// ---------------------------------------------------------------------------
// match: per-scale matching + positive losses. thread = pixel, 3 anchors each.
// Writes neg_key[b][SEG_OFF + a*HW + pix] = neg ? raw_obj_logit : -inf
// (selection on raw logits is exact: softplus is strictly monotone).
// GT y-band culling (block level) + largest-anchor gate (thread level):
// anchors share a center, so the a=2 box (half=2*stride) contains a=0/a=1.
// inter(a2,GT)==0  =>  all three IoUs are exactly 0 (reference computes 0 for
// them too), so gated GTs cannot change best (after fmax(best,0)) nor argmax
// (positives need IoU>=0.5>0; strict-> scan over increasing j keeps
// first-index semantics among surviving candidates).
// ---------------------------------------------------------------------------
template<int H, int SEG_OFF>
__device__ __forceinline__ void match_scale(
    const float* __restrict__ pred,      // (B, 24, H, H)
    const float* __restrict__ gt_boxes,  // (B, 20, 4)
    const int*   __restrict__ gt_labels, // (B, 20)
    float* __restrict__ neg_key,         // (B, N_TOT)
    int*   __restrict__ pos_cnt,         // (96,)
    float* __restrict__ sums,            // [obj_pos, cls, loc]
    int pixblk, int b, int pair)
{
    constexpr int HW = H * H;
    constexpr float STRIDE = 256.0f / (float)H;
    constexpr int NROWS = 256 / H;
    const int tid = threadIdx.x;
    const int pix = pixblk * 256 + tid;          // always < HW

    __shared__ float4 s_box[M_GT];
    __shared__ float  s_ag[M_GT];
    __shared__ int    s_lab[M_GT];
    __shared__ int    s_nk;

    if (tid < 64) {                               // wave 0 only: ballot compaction
        bool keep = false;
        float4 g = make_float4(0.f, 0.f, 0.f, 0.f);
        int lab = 0;
        if (tid < M_GT) {
            g   = reinterpret_cast<const float4*>(gt_boxes)[b * M_GT + tid];
            lab = gt_labels[b * M_GT + tid];
            const int y0 = (pixblk * 256) / H;
            const float lo = ((float)y0 + 0.5f) * STRIDE - 2.0f * STRIDE;
            const float hi = ((float)(y0 + NROWS - 1) + 0.5f) * STRIDE + 2.0f * STRIDE;
            keep = (g.y < hi) && (g.w > lo);      // y-overlap possible
        }
        unsigned long long m = __ballot(keep);
        if (keep) {
            int posi = __popcll(m & ((1ull << tid) - 1ull));   // order-preserving
            s_box[posi] = g;
            s_ag[posi]  = (g.z - g.x) * (g.w - g.y);
            s_lab[posi] = lab;
        }
        if (tid == 0) s_nk = __popcll(m);
    }
    __syncthreads();
    const int nk = s_nk;

    const int x = pix % H;                        // H is constexpr -> and/shift
    const int y = pix / H;
    const float cx = ((float)x + 0.5f) * STRIDE;  // exact fp32, == make_anchors
    const float cy = ((float)y + 0.5f) * STRIDE;
    const size_t pbase = (size_t)b * 24 * HW + pix;

    // largest anchor (a=2): half = 2*STRIDE (exact)
    const float axL1 = cx - 2.0f * STRIDE, ayL1 = cy - 2.0f * STRIDE;
    const float axL2 = cx + 2.0f * STRIDE, ayL2 = cy + 2.0f * STRIDE;

    float best[3] = {-1.f, -1.f, -1.f};
    int   bj[3]   = {0, 0, 0};

    for (int j = 0; j < nk; ++j) {
        const float4 gb = s_box[j];
        // gate: intersection with the LARGEST anchor (contains the others)
        const float glx = fmaxf(axL1, gb.x), gly = fmaxf(ayL1, gb.y);
        const float grx = fminf(axL2, gb.z), gry = fminf(ayL2, gb.w);
        if (grx <= glx || gry <= gly) continue;   // all three IoUs exactly 0
        const float ag = s_ag[j];
        #pragma unroll
        for (int a = 0; a < 3; ++a) {
            const float half = 0.5f * ((float)(a + 2) * STRIDE);
            const float ax1 = cx - half, ay1 = cy - half;
            const float ax2 = cx + half, ay2 = cy + half;
            const float aa = (ax2 - ax1) * (ay2 - ay1);
            float lx = fmaxf(ax1, gb.x);
            float ly = fmaxf(ay1, gb.y);
            float rx = fminf(ax2, gb.z);
            float ry = fminf(ay2, gb.w);
            float w  = fmaxf(rx - lx, 0.f);
            float h  = fmaxf(ry - ly, 0.f);
            float inter = w * h;
            float iou = inter / (aa + ag - inter + EPSF);
            if (iou > best[a]) { best[a] = iou; bj[a] = j; }   // first-max
        }
    }

    float l_obj = 0.f, l_cls = 0.f, l_loc = 0.f;
    int l_pos = 0;

    #pragma unroll
    for (int a = 0; a < 3; ++a) {
        const float ba = fmaxf(best[a], 0.0f);    // culled/gated GTs give 0
        const bool pos = (ba >= 0.5f);
        const bool neg = (ba < 0.3f);

        const float po = pred[pbase + (size_t)(a * 8 + 4) * HW];
        neg_key[(size_t)b * N_TOT + SEG_OFF + a * HW + pix] =
            neg ? po : __uint_as_float(SENT_BITS);

        if (pos) {
            const int j = bj[a];
            const float half = 0.5f * ((float)(a + 2) * STRIDE);
            const float ax1 = cx - half, ay1 = cy - half;
            const float ax2 = cx + half, ay2 = cy + half;
            l_pos += 1;
            l_obj += fmaxf(po, 0.f) - po + log1pf(expf(-fabsf(po)));  // t=1
            float c0 = pred[pbase + (size_t)(a * 8 + 5) * HW];
            float c1 = pred[pbase + (size_t)(a * 8 + 6) * HW];
            float c2 = pred[pbase + (size_t)(a * 8 + 7) * HW];
            float m2 = fmaxf(c0, fmaxf(c1, c2));
            float lse = m2 + logf(expf(c0 - m2) + expf(c1 - m2) + expf(c2 - m2));
            int tgt = s_lab[j];
            float lt = (tgt == 0) ? c0 : ((tgt == 1) ? c1 : c2);
            l_cls += lse - lt;
            float4 gb = s_box[j];
            float gw = fmaxf(gb.z - gb.x, EPSF), gh = fmaxf(gb.w - gb.y, EPSF);
            float gcx = gb.x + 0.5f * gw, gcy = gb.y + 0.5f * gh;
            float aw = fmaxf(ax2 - ax1, EPSF), ah = fmaxf(ay2 - ay1, EPSF);
            float acx = ax1 + 0.5f * aw, acy = ay1 + 0.5f * ah;
            float tx = (gcx - acx) / (aw + EPSF);
            float ty = (gcy - acy) / (ah + EPSF);
            float tw = logf((gw + EPSF) / (aw + EPSF));
            float th = logf((gh + EPSF) / (ah + EPSF));
            float p0 = pred[pbase + (size_t)(a * 8 + 0) * HW];
            float p1 = pred[pbase + (size_t)(a * 8 + 1) * HW];
            float p2 = pred[pbase + (size_t)(a * 8 + 2) * HW];
            float p3 = pred[pbase + (size_t)(a * 8 + 3) * HW];
            float d0 = p0 - tx, d1 = p1 - ty, d2 = p2 - tw, d3 = p3 - th;
            float ad;
            ad = fabsf(d0); l_loc += (ad < 1.f) ? 0.5f * d0 * d0 : ad - 0.5f;
            ad = fabsf(d1); l_loc += (ad < 1.f) ? 0.5f * d1 * d1 : ad - 0.5f;
            ad = fabsf(d2); l_loc += (ad < 1.f) ? 0.5f * d2 * d2 : ad - 0.5f;
            ad = fabsf(d3); l_loc += (ad < 1.f) ? 0.5f * d3 * d3 : ad - 0.5f;
        }
    }

    if (l_pos) {
        atomicAdd(&pos_cnt[pair], l_pos);
        atomicAdd(&sums[0], l_obj);
        atomicAdd(&sums[1], l_cls);
        atomicAdd(&sums[2], l_loc);
    }
}

__global__ __launch_bounds__(256) void match_kernel(
    const float* __restrict__ pred1, const float* __restrict__ pred2,
    const float* __restrict__ pred3, const float* __restrict__ gt_boxes,
    const int* __restrict__ gt_labels, float* __restrict__ neg_key,
    int* __restrict__ pos_cnt, float* __restrict__ sums)
{
    const int b  = blockIdx.y;
    const int bx = blockIdx.x;
    if (bx < 64)
        match_scale<128, 0>(pred1, gt_boxes, gt_labels, neg_key, pos_cnt, sums, bx, b, b * 3 + 0);
    else if (bx < 80)
        match_scale<64, 49152>(pred2, gt_boxes, gt_labels, neg_key, pos_cnt, sums, bx - 64, b, b * 3 + 1);
    else
        match_scale<32, 61440>(pred3, gt_boxes, gt_labels, neg_key, pos_cnt, sums, bx - 80, b, b * 3 + 2);
}

// ---------------------------------------------------------------------------
// Inclusive suffix-scan of x over 1024 threads (16 waves): intra-wave shfl
// suffix (6 steps, no barriers) + wave-total combine. Returns sum x[tid..1023];
// *tot_out = sum over all. Entry barrier protects wtot reuse across calls.
// ---------------------------------------------------------------------------
__device__ __forceinline__ int suffix_scan_1024(int x, int* wtot, int tid, int* tot_out) {
    const int lane = tid & 63, w = tid >> 6;
    int v = x;
    #pragma unroll
    for (int off = 1; off < 64; off <<= 1) {
        int u = __shfl_down(v, off);
        if (lane + off < 64) v += u;
    }
    __syncthreads();                 // protect wtot from previous use
    if (lane == 0) wtot[w] = v;      // wave suffix-total (lane0 covers whole wave)
    __syncthreads();
    int add = 0, tot = 0;
    #pragma unroll
    for (int j = 0; j < 16; ++j) {
        int t = wtot[j];
        tot += t;
        if (j > w) add += t;
    }
    *tot_out = tot;
    return v + add;
}

// ---------------------------------------------------------------------------
// mine: one 1024-thread block per (image, scale). Two MLP-unrolled global
// passes; parallel scans; exact 2x10-bit tie radix; last-block final output.
// ---------------------------------------------------------------------------
__global__ __launch_bounds__(MT) void mine_kernel(
    const float* __restrict__ neg_key,
    int*   pos_cnt,     // non-const: atomic reads in final reduce
    float* sums,
    int*   done,
    float* sel_sum,
    int*   sel_cnt,
    float* __restrict__ out)
{
    const int p = blockIdx.x;         // b*3 + s
    const int s = p % 3;
    const int b = p / 3;
    const int seg_off = (s == 0) ? 0 : (s == 1) ? 49152 : 61440;
    const int len4    = ((s == 0) ? 49152 : (s == 1) ? 12288 : 3072) >> 2;
    const float4* seg4 =
        reinterpret_cast<const float4*>(neg_key + (size_t)b * N_TOT + seg_off);
    const int tid = threadIdx.x;

    __shared__ int   hist[MBINS];     // 16 KB (reused for 1024-bin tie radix)
    __shared__ int   wtot[16];
    __shared__ float ties[TIE_CAP];   // 8 KB
    __shared__ float wpart[16];
    __shared__ int s_tcnt, s_tbin, s_kr, s_binA, s_krA, s_binB, s_krB, s_last;

    for (int i = tid; i < MBINS; i += MT) hist[i] = 0;
    if (tid == 0) s_tcnt = 0;
    __syncthreads();

    // ---- phase 1: histogram of key top-12 bits (4-deep unrolled loads) ----
    auto proc1 = [&](float x) {
        unsigned ub = __float_as_uint(x);
        if (ub != SENT_BITS) atomicAdd(&hist[keyof(ub) >> 20], 1);
    };
    {
        int i = tid;
        for (; i + 3 * MT < len4; i += 4 * MT) {
            float4 a0 = seg4[i], a1 = seg4[i + MT], a2 = seg4[i + 2 * MT], a3 = seg4[i + 3 * MT];
            proc1(a0.x); proc1(a0.y); proc1(a0.z); proc1(a0.w);
            proc1(a1.x); proc1(a1.y); proc1(a1.z); proc1(a1.w);
            proc1(a2.x); proc1(a2.y); proc1(a2.z); proc1(a2.w);
            proc1(a3.x); proc1(a3.y); proc1(a3.z); proc1(a3.w);
        }
        for (; i < len4; i += MT) {
            float4 a0 = seg4[i];
            proc1(a0.x); proc1(a0.y); proc1(a0.z); proc1(a0.w);
        }
    }
    __syncthreads();

    // ---- phase 2: parallel suffix scan locates threshold bin ----
    const int b0 = tid * 4;
    const int my = hist[b0] + hist[b0 + 1] + hist[b0 + 2] + hist[b0 + 3];
    int nneg;
    const int incl = suffix_scan_1024(my, wtot, tid, &nneg);
    const int k = 3 * max(pos_cnt[p], 1);
    const bool ta = (k >= nneg);
    if (!ta && (incl - my) < k && k <= incl) {    // boundary in my 4-bin chunk
        int cg = incl - my;                        // count strictly above chunk
        for (int bin = b0 + 3; bin >= b0; --bin) {
            int c = hist[bin];
            if (cg < k && k <= cg + c) { s_tbin = bin; s_kr = k - cg; break; }
            cg += c;
        }
    }
    __syncthreads();
    const int tbin = ta ? 0 : s_tbin;

    // ---- phase 3: sum softplus above tbin; gather tie-bin values ----
    float acc = 0.f;
    auto proc3 = [&](float x) {
        unsigned ub = __float_as_uint(x);
        if (ub == SENT_BITS) return;
        int bin = (int)(keyof(ub) >> 20);
        if (ta || bin > tbin) acc += softplus_ref(x);
        else if (bin == tbin) {
            int idx = atomicAdd(&s_tcnt, 1);
            if (idx < TIE_CAP) ties[idx] = x;
        }
    };
    {
        int i = tid;
        for (; i + 3 * MT < len4; i += 4 * MT) {
            float4 a0 = seg4[i], a1 = seg4[i + MT], a2 = seg4[i + 2 * MT], a3 = seg4[i + 3 * MT];
            proc3(a0.x); proc3(a0.y); proc3(a0.z); proc3(a0.w);
            proc3(a1.x); proc3(a1.y); proc3(a1.z); proc3(a1.w);
            proc3(a2.x); proc3(a2.y); proc3(a2.z); proc3(a2.w);
            proc3(a3.x); proc3(a3.y); proc3(a3.z); proc3(a3.w);
        }
        for (; i < len4; i += MT) {
            float4 a0 = seg4[i];
            proc3(a0.x); proc3(a0.y); proc3(a0.z); proc3(a0.w);
        }
    }
    #pragma unroll
    for (int off = 32; off > 0; off >>= 1) acc += __shfl_down(acc, off);
    __syncthreads();                  // all gathers done; s_tcnt final
    if ((tid & 63) == 0) wpart[tid >> 6] = acc;
    __syncthreads();
    float blocksum = 0.f;
    if (tid == 0) {
        #pragma unroll
        for (int j = 0; j < 16; ++j) blocksum += wpart[j];
    }

    // ---- phase 4: exact tie resolution (1 bin/thread, two 10-bit levels) ----
    float extra = 0.f;
    const int selcnt = ta ? nneg : k;
    if (!ta) {
        const int m  = min(s_tcnt, TIE_CAP);
        const int kr = s_kr;
        // level A: key bits [19:10]
        hist[tid] = 0;
        __syncthreads();
        for (int i = tid; i < m; i += MT)
            atomicAdd(&hist[(keyof(__float_as_uint(ties[i])) >> 10) & 1023], 1);
        __syncthreads();
        {
            int myA = hist[tid], totA;
            int inclA = suffix_scan_1024(myA, wtot, tid, &totA);
            if ((inclA - myA) < kr && kr <= inclA) { s_binA = tid; s_krA = kr - (inclA - myA); }
        }
        __syncthreads();
        const int binA = s_binA, krA = s_krA;
        // level B: key bits [9:0] among prefix matches
        hist[tid] = 0;
        __syncthreads();
        for (int i = tid; i < m; i += MT) {
            unsigned key = keyof(__float_as_uint(ties[i]));
            if (((key >> 10) & 1023) == (unsigned)binA) atomicAdd(&hist[key & 1023], 1);
        }
        __syncthreads();
        {
            int myB = hist[tid], totB;
            int inclB = suffix_scan_1024(myB, wtot, tid, &totB);
            if ((inclB - myB) < krA && krA <= inclB) { s_binB = tid; s_krB = krA - (inclB - myB); }
        }
        __syncthreads();
        const unsigned tkey = (((unsigned)tbin) << 20) | (((unsigned)binA) << 10)
                            | (unsigned)s_binB;
        float acc2 = 0.f;
        for (int i = tid; i < m; i += MT) {
            float x = ties[i];
            if (keyof(__float_as_uint(x)) > tkey) acc2 += softplus_ref(x);
        }
        #pragma unroll
        for (int off = 32; off > 0; off >>= 1) acc2 += __shfl_down(acc2, off);
        __syncthreads();              // protect wpart reuse (tid0 read blocksum)
        if ((tid & 63) == 0) wpart[tid >> 6] = acc2;
        __syncthreads();
        if (tid == 0) {
            float e2 = 0.f;
            #pragma unroll
            for (int j = 0; j < 16; ++j) e2 += wpart[j];
            const unsigned tb2 = (tkey & 0x80000000u) ? (tkey & 0x7FFFFFFFu) : ~tkey;
            extra = e2 + (float)s_krB * softplus_ref(__uint_as_float(tb2));
        }
    }

    // ---- publish + last-block final output ----
    if (tid == 0) {
        atomicExch(&sel_sum[p], blocksum + extra);
        atomicExch(&sel_cnt[p], selcnt);
        __threadfence();
        int old = atomicAdd(done, 1);
        s_last = (old == NPAIR - 1) ? 1 : 0;
    }
    __syncthreads();
    if (s_last) {
        __threadfence();
        float fs = 0.f; int c1 = 0, c2 = 0;
        if (tid < NPAIR) {
            fs = atomicAdd(&sel_sum[tid], 0.0f);   // coherent reads
            c1 = atomicAdd(&pos_cnt[tid], 0);
            c2 = atomicAdd(&sel_cnt[tid], 0);
        }
        #pragma unroll
        for (int off = 32; off > 0; off >>= 1) {
            fs += __shfl_down(fs, off);
            c1 += __shfl_down(c1, off);
            c2 += __shfl_down(c2, off);
        }
        __shared__ float f2[16]; __shared__ int a2[16], b2[16];
        if ((tid & 63) == 0) { f2[tid >> 6] = fs; a2[tid >> 6] = c1; b2[tid >> 6] = c2; }
        __syncthreads();
        if (tid == 0) {
            float obj    = atomicAdd(&sums[0], 0.0f) + f2[0] + f2[1];
            float clsum  = atomicAdd(&sums[1], 0.0f);
            float locsum = atomicAdd(&sums[2], 0.0f);
            int np  = a2[0] + a2[1];
            int den = np + b2[0] + b2[1];
            float pn = (float)max(np, 1);
            float on = (float)max(den, 1);
            float lo = obj / on, lc = clsum / pn, ll = locsum / pn;
            out[0] = lo; out[1] = lc; out[2] = ll;
            out[3] = lo + lc + 2.0f * ll;
        }
    }
}

// ---------------------------------------------------------------------------
extern "C" void kernel_launch(void* const* d_in, const int* in_sizes, int n_in,
                              void* d_out, int out_size, void* d_ws, size_t ws_size,
                              hipStream_t stream) {
    // setup_inputs() dict order: pred1, anchors1, pred2, anchors2, pred3,
    // anchors3, gt_boxes, gt_labels
    const float* pred1     = (const float*)d_in[0];   // (32,24,128,128)
    const float* pred2     = (const float*)d_in[2];   // (32,24,64,64)
    const float* pred3     = (const float*)d_in[4];   // (32,24,32,32)
    const float* gt_boxes  = (const float*)d_in[6];   // (32,20,4)
    const int*   gt_labels = (const int*)d_in[7];     // (32,20)

    char* ws = (char*)d_ws;
    float* sums    = (float*)(ws + 0);      // 3 floats
    int*   pos_cnt = (int*)  (ws + 16);     // 96 ints
    int*   done    = (int*)  (ws + 400);    // 1 int
    float* sel_sum = (float*)(ws + 512);    // 96 floats (atomicExch-published)
    int*   sel_cnt = (int*)  (ws + 896);    // 96 ints   (atomicExch-published)
    float* neg_key = (float*)(ws + 1280);   // 32*64512 floats = 8.25 MB

    hipMemsetAsync(d_ws, 0, 512, stream);   // sums + pos_cnt + done

    match_kernel<<<dim3(84, B_IMG), 256, 0, stream>>>(
        pred1, pred2, pred3, gt_boxes, gt_labels, neg_key, pos_cnt, sums);

    mine_kernel<<<NPAIR, MT, 0, stream>>>(
        neg_key, pos_cnt, sums, done, sel_sum, sel_cnt, (float*)d_out);
}